// Round 3
// baseline (1587.521 us; speedup 1.0000x reference)
//
#include <hip/hip_runtime.h>
#include <hip/hip_bf16.h>
#include <stdint.h>

#define LL 512
#define BB 64
#define CC 512

typedef float float4v __attribute__((ext_vector_type(4)));
typedef long long ll2 __attribute__((ext_vector_type(2)));

// ws layout:
//   [0, 262144)        : E8  = fp8(exp(trans))^T, layout [j][k], row stride 512 bytes
//   [262144, 262148)   : float scoreAcc
//   [262148, 262404)   : float logzArr[64]
#define WS_SCORE 262144
#define WS_LOGZ  262148

__device__ __forceinline__ bool mask_at(const void* maskp, bool is_byte, int t, int b) {
    if (is_byte) return ((const unsigned char*)maskp)[t * BB + b] != 0;
    return ((const int*)maskp)[t * BB + b] != 0;
}

// ---------------- prep: build E8 = fp8(exp(trans))^T, zero score accumulator ----------
__global__ void prep_kernel(const float* __restrict__ trans, unsigned char* __restrict__ ws) {
    int g = blockIdx.x * blockDim.x + threadIdx.x;
    if (g == 0) *(float*)(ws + WS_SCORE) = 0.0f;
    if (g >= 512 * 128) return;
    int j  = g & 511;      // output col (N index)
    int k4 = g >> 9;       // dword along k
    float e0 = __expf(trans[(4 * k4 + 0) * CC + j]);
    float e1 = __expf(trans[(4 * k4 + 1) * CC + j]);
    float e2 = __expf(trans[(4 * k4 + 2) * CC + j]);
    float e3 = __expf(trans[(4 * k4 + 3) * CC + j]);
    int r = 0;
    r = __builtin_amdgcn_cvt_pk_fp8_f32(e0, e1, r, false);
    r = __builtin_amdgcn_cvt_pk_fp8_f32(e2, e3, r, true);
    ((int*)ws)[j * 128 + k4] = r;
}

// p8 layout per chain row (stride 528 B): byte for k-index j at
//   F(j) = ((j>>3)&3)*128 + (j>>5)*8 + (j&7)     (digit-swap bijection)
// => lane (r15,q)'s A-fragment (k = kk*32+q*8+b) is 128 CONTIGUOUS bytes at
//    r15*528 + q*128  -> 8x ds_read_b128.

// ---------------- main scan: 4 wgs x 512 thr, 16 chains per wg -----------------------
// Prob-space scan with EXACT per-step normalization (same numerics as R1):
//   compute: vn = (P_{t-1} @ E) * exp(emit_t)  (MFMA, registers)
//   barrier; convert: P_t = vn / M_t (pv <= 1, fp8-safe), Sv += log(M_t); barrier.
// Final logsumexp accumulated incrementally at each chain's last active step.
__launch_bounds__(512, 2)
__global__ void crf_scan_kernel(const float* __restrict__ emit,
                                const void* __restrict__ maskp,
                                const float* __restrict__ tfs,
                                const float* __restrict__ t2e,
                                unsigned char* __restrict__ ws) {
    __shared__ __align__(16) unsigned char p8[2][16 * 528];  // fp8 P, double-buffered
    __shared__ float mslot[2][16];   // per-chain rowmax, 2-slot ring
    __shared__ float Sv[16];         // log-scale accumulator
    __shared__ float dotS[16];       // final  sum_j P_j * exp(t2e_j)
    __shared__ float m0S[16];
    __shared__ float red[16][32];
    __shared__ int   lenS[16];

    const int tid = threadIdx.x;
    const int B0  = blockIdx.x * 16;
    const bool is_byte = ((const unsigned char*)maskp)[1] != 0;

    const int wv   = tid >> 6;   // wave 0..7, owns n-tiles wv*4..wv*4+3
    const int lane = tid & 63;
    const int q    = lane >> 4;  // k-group / C-row-group
    const int r15  = lane & 15;  // B col / A row within tile

    // E fragments: resident in VGPRs for all 511 steps
    long long ef[4][16];
#pragma unroll
    for (int nt = 0; nt < 4; ++nt) {
        int j = (wv * 4 + nt) * 16 + r15;
#pragma unroll
        for (int kk = 0; kk < 16; ++kk)
            ef[nt][kk] = *(const long long*)(ws + j * 512 + kk * 32 + q * 8);
    }

    const int c5 = tid >> 5;  // chain 0..15
    const int s5 = tid & 31;  // slice 0..31

    // ---- init pass 1: per-chain m0 = max(emit[0] + tfs) ----
    {
        float lmax = -3.0e38f;
#pragma unroll
        for (int i = 0; i < 4; ++i) {
            int j4 = s5 + 32 * i;
            float4v em = *(const float4v*)(emit + (size_t)(B0 + c5) * CC + 4 * j4);
            float4v tf = *(const float4v*)(tfs + 4 * j4);
            float4v a = em + tf;
            lmax = fmaxf(lmax, fmaxf(fmaxf(a.x, a.y), fmaxf(a.z, a.w)));
        }
        red[c5][s5] = lmax;
    }
    __syncthreads();
    if (tid < 16) {
        float m0 = red[tid][0];
        for (int s = 1; s < 32; ++s) m0 = fmaxf(m0, red[tid][s]);
        Sv[tid]  = m0;
        m0S[tid] = m0;
        mslot[0][tid] = 0.0f;
        mslot[1][tid] = 0.0f;   // step 1's atomicMax target
        dotS[tid] = 0.0f;
    }
    __syncthreads();
    // ---- init pass 2: P_0 = exp(alpha0 - m0) -> fp8 into p8[0]; chain lengths ----
    {
        float m0 = m0S[c5];
#pragma unroll
        for (int i = 0; i < 4; ++i) {
            int j4 = s5 + 32 * i;
            float4v em = *(const float4v*)(emit + (size_t)(B0 + c5) * CC + 4 * j4);
            float4v tf = *(const float4v*)(tfs + 4 * j4);
            float4v a = em + tf;
            float fx = __expf(a.x - m0), fy = __expf(a.y - m0);
            float fz = __expf(a.z - m0), fw = __expf(a.w - m0);
            int r = 0;
            r = __builtin_amdgcn_cvt_pk_fp8_f32(fx, fy, r, false);
            r = __builtin_amdgcn_cvt_pk_fp8_f32(fz, fw, r, true);
            int off = c5 * 528 + ((j4 >> 1) & 3) * 128 + (j4 >> 3) * 8 + (j4 & 1) * 4;
            *(int*)(&p8[0][0] + off) = r;
        }
        int part = 0;
        for (int k = 0; k < 16; ++k)
            part += mask_at(maskp, is_byte, s5 * 16 + k, B0 + c5) ? 1 : 0;
        red[c5][s5] = (float)part;
    }
    __syncthreads();
    if (tid < 16) {
        int s = 0;
        for (int i = 0; i < 32; ++i) s += (int)red[tid][i];
        lenS[tid] = s;   // lens >= 256 per problem spec
    }
    __syncthreads();

    int lenR[4];
    float et2e[4];
#pragma unroll
    for (int rr = 0; rr < 4; ++rr) lenR[rr] = lenS[q * 4 + rr];
#pragma unroll
    for (int nt = 0; nt < 4; ++nt)
        et2e[nt] = __expf(t2e[(wv * 4 + nt) * 16 + r15]);

    // emit pipeline: em holds step t's values
    float em[16];
#pragma unroll
    for (int nt = 0; nt < 4; ++nt)
#pragma unroll
        for (int rr = 0; rr < 4; ++rr)
            em[nt * 4 + rr] =
                emit[(size_t)(1 * BB + B0 + q * 4 + rr) * CC + (wv * 4 + nt) * 16 + r15];

    // ---- main loop: two barriers per step, all state in registers ----
    for (int t = 1; t < LL; ++t) {
        const int wp = t & 1;      // write parity
        const int rp = wp ^ 1;     // read parity

        // prefetch next step's emit (full step of latency slack)
        float emn[16];
        {
            int tn = (t < LL - 1) ? t + 1 : t;
#pragma unroll
            for (int nt = 0; nt < 4; ++nt)
#pragma unroll
                for (int rr = 0; rr < 4; ++rr)
                    emn[nt * 4 + rr] =
                        emit[(size_t)(tn * BB + B0 + q * 4 + rr) * CC + (wv * 4 + nt) * 16 + r15];
        }

        // reset the slot step t+1 will atomicMax (slot (t+1)&1; untouched this step)
        if (wv == 0 && r15 == 0) {
#pragma unroll
            for (int rr = 0; rr < 4; ++rr) mslot[(t + 1) & 1][q * 4 + rr] = 0.0f;
        }

        // A fragments: 8x ds_read_b128, contiguous per lane
        long long af[16];
        const unsigned char* pr = &p8[rp][0] + r15 * 528 + q * 128;
#pragma unroll
        for (int i = 0; i < 8; ++i) {
            ll2 v = *(const ll2*)(pr + 16 * i);
            af[2 * i] = v.x;
            af[2 * i + 1] = v.y;
        }

        float4v acc[4];
        const float4v z = {0.f, 0.f, 0.f, 0.f};
#pragma unroll
        for (int nt = 0; nt < 4; ++nt) acc[nt] = z;
#pragma unroll
        for (int kk = 0; kk < 16; ++kk)
#pragma unroll
            for (int nt = 0; nt < 4; ++nt)
                acc[nt] = __builtin_amdgcn_mfma_f32_16x16x32_fp8_fp8(af[kk], ef[nt][kk], acc[nt], 0, 0, 0);

        // vn = acc * exp(emit); per-chain rowmax -> mslot[t&1]
        float rowmax[4] = {0.f, 0.f, 0.f, 0.f};
#pragma unroll
        for (int nt = 0; nt < 4; ++nt)
#pragma unroll
            for (int rr = 0; rr < 4; ++rr) {
                float vn = acc[nt][rr] * __expf(em[nt * 4 + rr]);
                acc[nt][rr] = vn;
                rowmax[rr] = fmaxf(rowmax[rr], vn);
            }
#pragma unroll
        for (int rr = 0; rr < 4; ++rr) {
            float mr = rowmax[rr];
            mr = fmaxf(mr, __shfl_xor(mr, 1));
            mr = fmaxf(mr, __shfl_xor(mr, 2));
            mr = fmaxf(mr, __shfl_xor(mr, 4));
            mr = fmaxf(mr, __shfl_xor(mr, 8));
            if (r15 == 0 && t < lenR[rr])
                atomicMax((int*)&mslot[t & 1][q * 4 + rr], __float_as_int(mr)); // vn > 0
        }
        __syncthreads();   // barrier 1: M_t complete

        // convert phase: P_t = vn / M_t (exact, pv <= 1); Sv, final-dot bookkeeping
        float Mc[4], rcv[4];
#pragma unroll
        for (int rr = 0; rr < 4; ++rr) {
            Mc[rr]  = mslot[t & 1][q * 4 + rr];   // broadcast read
            rcv[rr] = 1.0f / Mc[rr];              // inf only for frozen chains (unused)
        }
#pragma unroll
        for (int nt = 0; nt < 4; ++nt) {
            int tile = wv * 4 + nt;
            int boff = ((tile & 1) * 2 + (r15 >> 3)) * 128 + (tile >> 1) * 8 + (r15 & 7);
#pragma unroll
            for (int rr = 0; rr < 4; ++rr) {
                if (t < lenR[rr]) {
                    float pv = acc[nt][rr] * rcv[rr];
                    int r = __builtin_amdgcn_cvt_pk_fp8_f32(pv, pv, 0, false);
                    p8[wp][(q * 4 + rr) * 528 + boff] = (unsigned char)(r & 0xff);
                }
            }
        }
        if (wv == 0 && r15 == 0) {
#pragma unroll
            for (int rr = 0; rr < 4; ++rr)
                if (t < lenR[rr]) Sv[q * 4 + rr] += __logf(Mc[rr]);
        }
#pragma unroll
        for (int rr = 0; rr < 4; ++rr) {
            if (t == lenR[rr] - 1) {   // uniform across the 16-lane quad
                float part = 0.0f;
#pragma unroll
                for (int nt = 0; nt < 4; ++nt)
                    part += acc[nt][rr] * rcv[rr] * et2e[nt];
                part += __shfl_xor(part, 1);
                part += __shfl_xor(part, 2);
                part += __shfl_xor(part, 4);
                part += __shfl_xor(part, 8);
                if (r15 == 0) atomicAdd(&dotS[q * 4 + rr], part);
            }
        }
        // rotate emit pipeline
#pragma unroll
        for (int i = 0; i < 16; ++i) em[i] = emn[i];
        __syncthreads();   // barrier 2
    }

    if (tid < 16)
        ((float*)(ws + WS_LOGZ))[B0 + tid] = Sv[tid] + __logf(dotS[tid]);
}

// ---------------- score: gather terms, atomic accumulate -----------------------------
__global__ void score_kernel(const float* __restrict__ emit,
                             const int* __restrict__ target,
                             const void* __restrict__ maskp,
                             const float* __restrict__ trans,
                             const float* __restrict__ tfs,
                             const float* __restrict__ t2e,
                             unsigned char* __restrict__ ws) {
    const bool is_byte = ((const unsigned char*)maskp)[1] != 0;
    int g = blockIdx.x * blockDim.x + threadIdx.x;
    float val = 0.0f;
    for (int e = g; e < LL * BB; e += gridDim.x * blockDim.x) {
        int t = e >> 6, b = e & 63;
        if (mask_at(maskp, is_byte, t, b)) {
            int tg  = target[t * BB + b];
            float v = emit[(size_t)(t * BB + b) * CC + tg];
            if (t > 0) v += trans[(size_t)target[(t - 1) * BB + b] * CC + tg];
            val += v;
        }
    }
    if (blockIdx.x == 0 && threadIdx.x < BB) {
        int b = threadIdx.x;
        val += tfs[target[b]];
        int lo = 0, hi = LL;
        while (lo < hi) {
            int mid = (lo + hi) >> 1;
            if (mask_at(maskp, is_byte, mid, b)) lo = mid + 1; else hi = mid;
        }
        val += t2e[target[(lo - 1) * BB + b]];
    }
    for (int off = 32; off > 0; off >>= 1) val += __shfl_down(val, off);
    if ((threadIdx.x & 63) == 0) atomicAdd((float*)(ws + WS_SCORE), val);
}

// ---------------- combine: out = (sum logz - score)/B --------------------------------
__global__ void combine_kernel(const unsigned char* __restrict__ ws, float* __restrict__ out) {
    float v = ((const float*)(ws + WS_LOGZ))[threadIdx.x];
    for (int off = 32; off > 0; off >>= 1) v += __shfl_down(v, off);
    if (threadIdx.x == 0) out[0] = (v - *(const float*)(ws + WS_SCORE)) * (1.0f / 64.0f);
}

extern "C" void kernel_launch(void* const* d_in, const int* in_sizes, int n_in,
                              void* d_out, int out_size, void* d_ws, size_t ws_size,
                              hipStream_t stream) {
    const float* emit   = (const float*)d_in[0];
    const int*   target = (const int*)d_in[1];
    const void*  maskp  = d_in[2];
    const float* trans  = (const float*)d_in[3];
    const float* tfs    = (const float*)d_in[4];
    const float* t2e    = (const float*)d_in[5];
    unsigned char* ws   = (unsigned char*)d_ws;
    float* out          = (float*)d_out;

    prep_kernel<<<256, 256, 0, stream>>>(trans, ws);
    crf_scan_kernel<<<4, 512, 0, stream>>>(emit, maskp, tfs, t2e, ws);
    score_kernel<<<32, 256, 0, stream>>>(emit, target, maskp, trans, tfs, t2e, ws);
    combine_kernel<<<1, 64, 0, stream>>>(ws, out);
}

// Round 4
// 1263.675 us; speedup vs baseline: 1.2563x; 1.2563x over previous
//
#include <hip/hip_runtime.h>
#include <hip/hip_bf16.h>
#include <stdint.h>

#define LL 512
#define BB 64
#define CC 512

typedef float float4v __attribute__((ext_vector_type(4)));
typedef int   int4v   __attribute__((ext_vector_type(4)));
typedef int   int8v   __attribute__((ext_vector_type(8)));

// ws layout:
//   [0, 262144)        : E8T — fp8(exp(trans)) in PERMUTED position order (see below)
//   [262144, 262148)   : float scoreAcc
//   [262148, 262404)   : float logzArr[64]
#define WS_SCORE 262144
#define WS_LOGZ  262148

// ---- shared position permutation -----------------------------------------------------
// p8 row (per chain) = 512 bytes. Byte position P holds the value for class index
//   k_perm(P) = 64*(P>>6) + 16*(P&3) + ((P>>2)&15)
// Writer: lane (wv,q,r15) packs dword pd = wv*16+r15 (bytes nt=0..3 -> k = 64wv+16nt+r15)
//         into row c = q*4+rr  -> 4x ds_write_b32, 2-way bank conflict (free).
// Reader: lane (q,r15) feeds MFMA kk4 from bytes [kk4*128 + q*32, +32) -> 8x ds_read_b128,
//         uniform 8 dwords/bank (optimal).
// E8T[n][P] = fp8(exp(trans[k_perm(P)][n])) uses the SAME position map, so whatever
// (lane,byte)->k slot map the f8f6f4 MFMA uses, A and B agree slot-by-slot and the
// dot over k is exact. All MX scales = 0x7F (1.0).

__device__ __forceinline__ bool mask_at(const void* maskp, bool is_byte, int t, int b) {
    if (is_byte) return ((const unsigned char*)maskp)[t * BB + b] != 0;
    return ((const int*)maskp)[t * BB + b] != 0;
}

// ---------------- prep: build E8T (permuted), zero score accumulator ----------------
__global__ void prep_kernel(const float* __restrict__ trans, unsigned char* __restrict__ ws) {
    int g = blockIdx.x * blockDim.x + threadIdx.x;   // 65536 threads
    if (g == 0) *(float*)(ws + WS_SCORE) = 0.0f;
    if (g >= 512 * 128) return;
    int n  = g & 511;      // output col (N / class index of E's column)
    int pd = g >> 9;       // dword position within row, [0,128)
    int wv = pd >> 4, rw = pd & 15;
    float f[4];
#pragma unroll
    for (int nt = 0; nt < 4; ++nt) {
        int k = 64 * wv + 16 * nt + rw;
        f[nt] = __expf(trans[(size_t)k * CC + n]);
    }
    int r = 0;
    r = __builtin_amdgcn_cvt_pk_fp8_f32(f[0], f[1], r, false);
    r = __builtin_amdgcn_cvt_pk_fp8_f32(f[2], f[3], r, true);
    ((int*)ws)[n * 128 + pd] = r;
}

// ---------------- main scan: 4 wgs x 512 thr, 16 chains per wg -----------------------
__launch_bounds__(512, 2)
__global__ void crf_scan_kernel(const float* __restrict__ emit,
                                const void* __restrict__ maskp,
                                const float* __restrict__ tfs,
                                const float* __restrict__ t2e,
                                unsigned char* __restrict__ ws) {
    __shared__ __align__(16) unsigned char p8[2][16 * 528];  // fp8 P rows, double-buffered
    __shared__ float mslot[2][16];   // per-chain rowmax, 2-slot ring
    __shared__ float Sv[16];         // log-scale accumulator
    __shared__ float dotS[16];       // final sum_j P_j * exp(t2e_j)
    __shared__ float m0S[16];
    __shared__ float red[16][32];
    __shared__ int   lenS[16];

    const int tid = threadIdx.x;
    const int B0  = blockIdx.x * 16;
    const bool is_byte = ((const unsigned char*)maskp)[1] != 0;

    const int wv   = tid >> 6;   // wave 0..7, owns n-tiles wv*4..wv*4+3
    const int lane = tid & 63;
    const int q    = lane >> 4;
    const int r15  = lane & 15;

    // E fragments (B operand), resident for all steps: 4 nt x 4 kk4 x 8 dwords
    int8v ef[4][4];
#pragma unroll
    for (int nt = 0; nt < 4; ++nt) {
        int n = (wv * 4 + nt) * 16 + r15;
#pragma unroll
        for (int kk4 = 0; kk4 < 4; ++kk4) {
            const unsigned char* src = ws + n * 512 + kk4 * 128 + q * 32;
            int4v lo = *(const int4v*)(src);
            int4v hi = *(const int4v*)(src + 16);
            int8v v;
            v[0] = lo.x; v[1] = lo.y; v[2] = lo.z; v[3] = lo.w;
            v[4] = hi.x; v[5] = hi.y; v[6] = hi.z; v[7] = hi.w;
            ef[nt][kk4] = v;
        }
    }

    const int c5 = tid >> 5;  // chain 0..15
    const int s5 = tid & 31;  // slice 0..31

    // ---- init pass 1: per-chain m0 = max(emit[0] + tfs) ----
    {
        float lmax = -3.0e38f;
#pragma unroll
        for (int i = 0; i < 4; ++i) {
            int j4 = s5 + 32 * i;
            float4v em = *(const float4v*)(emit + (size_t)(B0 + c5) * CC + 4 * j4);
            float4v tf = *(const float4v*)(tfs + 4 * j4);
            float4v a = em + tf;
            lmax = fmaxf(lmax, fmaxf(fmaxf(a.x, a.y), fmaxf(a.z, a.w)));
        }
        red[c5][s5] = lmax;
    }
    __syncthreads();
    if (tid < 16) {
        float m0 = red[tid][0];
        for (int s = 1; s < 32; ++s) m0 = fmaxf(m0, red[tid][s]);
        Sv[tid]  = m0;
        m0S[tid] = m0;
        mslot[0][tid] = 0.0f;
        mslot[1][tid] = 0.0f;
        dotS[tid] = 0.0f;
    }
    __syncthreads();
    // ---- init pass 2: P_0 -> p8[0] in permuted layout; chain lengths ----
    {
        float m0 = m0S[c5];
#pragma unroll
        for (int i = 0; i < 4; ++i) {
            int pd = s5 + 32 * i;                 // dword position [0,128)
            int wvv = pd >> 4, rw = pd & 15;
            float f[4];
#pragma unroll
            for (int nt = 0; nt < 4; ++nt) {
                int k = 64 * wvv + 16 * nt + rw;
                f[nt] = __expf(emit[(size_t)(B0 + c5) * CC + k] + tfs[k] - m0);
            }
            int r = 0;
            r = __builtin_amdgcn_cvt_pk_fp8_f32(f[0], f[1], r, false);
            r = __builtin_amdgcn_cvt_pk_fp8_f32(f[2], f[3], r, true);
            *(int*)(&p8[0][0] + c5 * 528 + pd * 4) = r;
        }
        int part = 0;
        for (int k = 0; k < 16; ++k)
            part += mask_at(maskp, is_byte, s5 * 16 + k, B0 + c5) ? 1 : 0;
        red[c5][s5] = (float)part;
    }
    __syncthreads();
    if (tid < 16) {
        int s = 0;
        for (int i = 0; i < 32; ++i) s += (int)red[tid][i];
        lenS[tid] = s;   // lens >= 256 per problem spec
    }
    __syncthreads();

    int lenR[4];
    float et2e[4];
#pragma unroll
    for (int rr = 0; rr < 4; ++rr) lenR[rr] = lenS[q * 4 + rr];
#pragma unroll
    for (int nt = 0; nt < 4; ++nt)
        et2e[nt] = __expf(t2e[(wv * 4 + nt) * 16 + r15]);

    // emit: single base pointer, 16 immediate offsets (rr*2048B + nt*64B), +131072B/step
    const float* eb = emit + (size_t)(BB + B0 + q * 4) * CC + (wv * 64 + r15);
    float em[16];
#pragma unroll
    for (int nt = 0; nt < 4; ++nt)
#pragma unroll
        for (int rr = 0; rr < 4; ++rr)
            em[nt * 4 + rr] = eb[rr * CC + nt * 16];

    // ---- main loop ----
    for (int t = 1; t < LL; ++t) {
        const int wp = t & 1;
        const int rp = wp ^ 1;

        // prefetch next step's emit
        const float* ebn = (t < LL - 1) ? (eb + BB * CC) : eb;
        float emn[16];
#pragma unroll
        for (int nt = 0; nt < 4; ++nt)
#pragma unroll
            for (int rr = 0; rr < 4; ++rr)
                emn[nt * 4 + rr] = ebn[rr * CC + nt * 16];

        if (wv == 0 && r15 == 0) {
#pragma unroll
            for (int rr = 0; rr < 4; ++rr) mslot[(t + 1) & 1][q * 4 + rr] = 0.0f;
        }

        // A fragments: 8x ds_read_b128 (32B per kk4)
        int8v af[4];
        const unsigned char* pr = &p8[rp][0] + r15 * 528 + q * 32;
#pragma unroll
        for (int kk4 = 0; kk4 < 4; ++kk4) {
            int4v lo = *(const int4v*)(pr + kk4 * 128);
            int4v hi = *(const int4v*)(pr + kk4 * 128 + 16);
            int8v v;
            v[0] = lo.x; v[1] = lo.y; v[2] = lo.z; v[3] = lo.w;
            v[4] = hi.x; v[5] = hi.y; v[6] = hi.z; v[7] = hi.w;
            af[kk4] = v;
        }

        float4v acc[4];
        const float4v z = {0.f, 0.f, 0.f, 0.f};
#pragma unroll
        for (int nt = 0; nt < 4; ++nt) acc[nt] = z;
#pragma unroll
        for (int kk4 = 0; kk4 < 4; ++kk4)
#pragma unroll
            for (int nt = 0; nt < 4; ++nt)
                acc[nt] = __builtin_amdgcn_mfma_scale_f32_16x16x128_f8f6f4(
                    af[kk4], ef[nt][kk4], acc[nt],
                    0, 0,                 // cbsz=fp8 e4m3, blgp=fp8 e4m3
                    0, 0x7F7F7F7F,        // opsel_a, scale_a (=1.0)
                    0, 0x7F7F7F7F);       // opsel_b, scale_b (=1.0)

        // vn = acc * exp(emit); per-chain rowmax -> mslot[t&1]
        float rowmax[4] = {0.f, 0.f, 0.f, 0.f};
#pragma unroll
        for (int nt = 0; nt < 4; ++nt)
#pragma unroll
            for (int rr = 0; rr < 4; ++rr) {
                float vn = acc[nt][rr] * __expf(em[nt * 4 + rr]);
                acc[nt][rr] = vn;
                rowmax[rr] = fmaxf(rowmax[rr], vn);
            }
#pragma unroll
        for (int rr = 0; rr < 4; ++rr) {
            float mr = rowmax[rr];
            mr = fmaxf(mr, __shfl_xor(mr, 1));
            mr = fmaxf(mr, __shfl_xor(mr, 2));
            mr = fmaxf(mr, __shfl_xor(mr, 4));
            mr = fmaxf(mr, __shfl_xor(mr, 8));
            if (r15 == 0 && t < lenR[rr])
                atomicMax((int*)&mslot[t & 1][q * 4 + rr], __float_as_int(mr)); // vn > 0
        }
        __syncthreads();   // barrier 1: M_t complete

        // convert: P_t = vn / M_t (pv <= 1, fp8-safe); Sv, final-dot bookkeeping
        float Mc[4], rcv[4];
#pragma unroll
        for (int rr = 0; rr < 4; ++rr) {
            Mc[rr]  = mslot[t & 1][q * 4 + rr];
            rcv[rr] = 1.0f / Mc[rr];
        }
        // pack 4 nt-bytes per chain-row -> one ds_write_b32 at dword pd = wv*16+r15
        {
            unsigned char* wrow = &p8[wp][0] + (wv * 16 + r15) * 4;
#pragma unroll
            for (int rr = 0; rr < 4; ++rr) {
                if (t < lenR[rr]) {
                    int r = 0;
                    r = __builtin_amdgcn_cvt_pk_fp8_f32(acc[0][rr] * rcv[rr],
                                                        acc[1][rr] * rcv[rr], r, false);
                    r = __builtin_amdgcn_cvt_pk_fp8_f32(acc[2][rr] * rcv[rr],
                                                        acc[3][rr] * rcv[rr], r, true);
                    *(int*)(wrow + (q * 4 + rr) * 528) = r;
                }
            }
        }
        if (wv == 0 && r15 == 0) {
#pragma unroll
            for (int rr = 0; rr < 4; ++rr)
                if (t < lenR[rr]) Sv[q * 4 + rr] += __logf(Mc[rr]);
        }
#pragma unroll
        for (int rr = 0; rr < 4; ++rr) {
            if (t == lenR[rr] - 1) {   // uniform across the 16-lane quad
                float part = 0.0f;
#pragma unroll
                for (int nt = 0; nt < 4; ++nt)
                    part += acc[nt][rr] * rcv[rr] * et2e[nt];
                part += __shfl_xor(part, 1);
                part += __shfl_xor(part, 2);
                part += __shfl_xor(part, 4);
                part += __shfl_xor(part, 8);
                if (r15 == 0) atomicAdd(&dotS[q * 4 + rr], part);
            }
        }
#pragma unroll
        for (int i = 0; i < 16; ++i) em[i] = emn[i];
        eb += BB * CC;
        __syncthreads();   // barrier 2
    }

    if (tid < 16)
        ((float*)(ws + WS_LOGZ))[B0 + tid] = Sv[tid] + __logf(dotS[tid]);
}

// ---------------- score: gather terms, atomic accumulate -----------------------------
__global__ void score_kernel(const float* __restrict__ emit,
                             const int* __restrict__ target,
                             const void* __restrict__ maskp,
                             const float* __restrict__ trans,
                             const float* __restrict__ tfs,
                             const float* __restrict__ t2e,
                             unsigned char* __restrict__ ws) {
    const bool is_byte = ((const unsigned char*)maskp)[1] != 0;
    int g = blockIdx.x * blockDim.x + threadIdx.x;
    float val = 0.0f;
    for (int e = g; e < LL * BB; e += gridDim.x * blockDim.x) {
        int t = e >> 6, b = e & 63;
        if (mask_at(maskp, is_byte, t, b)) {
            int tg  = target[t * BB + b];
            float v = emit[(size_t)(t * BB + b) * CC + tg];
            if (t > 0) v += trans[(size_t)target[(t - 1) * BB + b] * CC + tg];
            val += v;
        }
    }
    if (blockIdx.x == 0 && threadIdx.x < BB) {
        int b = threadIdx.x;
        val += tfs[target[b]];
        int lo = 0, hi = LL;
        while (lo < hi) {
            int mid = (lo + hi) >> 1;
            if (mask_at(maskp, is_byte, mid, b)) lo = mid + 1; else hi = mid;
        }
        val += t2e[target[(lo - 1) * BB + b]];
    }
    for (int off = 32; off > 0; off >>= 1) val += __shfl_down(val, off);
    if ((threadIdx.x & 63) == 0) atomicAdd((float*)(ws + WS_SCORE), val);
}

// ---------------- combine: out = (sum logz - score)/B --------------------------------
__global__ void combine_kernel(const unsigned char* __restrict__ ws, float* __restrict__ out) {
    float v = ((const float*)(ws + WS_LOGZ))[threadIdx.x];
    for (int off = 32; off > 0; off >>= 1) v += __shfl_down(v, off);
    if (threadIdx.x == 0) out[0] = (v - *(const float*)(ws + WS_SCORE)) * (1.0f / 64.0f);
}

extern "C" void kernel_launch(void* const* d_in, const int* in_sizes, int n_in,
                              void* d_out, int out_size, void* d_ws, size_t ws_size,
                              hipStream_t stream) {
    const float* emit   = (const float*)d_in[0];
    const int*   target = (const int*)d_in[1];
    const void*  maskp  = d_in[2];
    const float* trans  = (const float*)d_in[3];
    const float* tfs    = (const float*)d_in[4];
    const float* t2e    = (const float*)d_in[5];
    unsigned char* ws   = (unsigned char*)d_ws;
    float* out          = (float*)d_out;

    prep_kernel<<<256, 256, 0, stream>>>(trans, ws);
    crf_scan_kernel<<<4, 512, 0, stream>>>(emit, maskp, tfs, t2e, ws);
    score_kernel<<<32, 256, 0, stream>>>(emit, target, maskp, trans, tfs, t2e, ws);
    combine_kernel<<<1, 64, 0, stream>>>(ws, out);
}

// Round 7
// 1152.915 us; speedup vs baseline: 1.3770x; 1.0961x over previous
//
#include <hip/hip_runtime.h>
#include <hip/hip_bf16.h>
#include <stdint.h>

#define LL 512
#define BB 64
#define CC 512

typedef float float4v __attribute__((ext_vector_type(4)));
typedef int   int4v   __attribute__((ext_vector_type(4)));
typedef int   int8v   __attribute__((ext_vector_type(8)));

#define WS_SCORE 262144
#define WS_LOGZ  262148

// position permutation shared by p8 rows and E8T columns:
//   k_perm(P) = 64*(P>>6) + 16*(P&3) + ((P>>2)&15)

__device__ __forceinline__ bool mask_at(const void* maskp, bool is_byte, int t, int b) {
    if (is_byte) return ((const unsigned char*)maskp)[t * BB + b] != 0;
    return ((const int*)maskp)[t * BB + b] != 0;
}

__global__ void prep_kernel(const float* __restrict__ trans, unsigned char* __restrict__ ws) {
    int g = blockIdx.x * blockDim.x + threadIdx.x;
    if (g == 0) *(float*)(ws + WS_SCORE) = 0.0f;
    if (g >= 512 * 128) return;
    int n  = g & 511;
    int pd = g >> 9;
    int wv = pd >> 4, rw = pd & 15;
    float f[4];
#pragma unroll
    for (int nt = 0; nt < 4; ++nt) {
        int k = 64 * wv + 16 * nt + rw;
        f[nt] = __expf(trans[(size_t)k * CC + n]);
    }
    int r = 0;
    r = __builtin_amdgcn_cvt_pk_fp8_f32(f[0], f[1], r, false);
    r = __builtin_amdgcn_cvt_pk_fp8_f32(f[2], f[3], r, true);
    ((int*)ws)[n * 128 + pd] = r;
}

// ---------------- main scan: ONE barrier per step, self-normalizing stale scale --------
// sigma_t = 64 * M_{t-1} / sigma_{t-1}  (ratio form). In log2: stored-max_t = g_t - 6
// EXACTLY and memorylessly (the sigma recursion cancels frame drift; sigma_t -> G_{t-1}).
// Sv accumulates log sigma_t in float (exact algebra: we log the exact sigma divided by).
__launch_bounds__(512, 2)
__global__ void crf_scan_kernel(const float* __restrict__ emit,
                                const void* __restrict__ maskp,
                                const float* __restrict__ tfs,
                                const float* __restrict__ t2e,
                                unsigned char* __restrict__ ws) {
    __shared__ __align__(16) unsigned char p8[2][16 * 528];
    __shared__ float mslot[4][16];   // rowmax ring; slot t&3 written at step t
    __shared__ float Sv[16];
    __shared__ float dotS[16];
    __shared__ float m0S[16];
    __shared__ float red[16][32];
    __shared__ int   lenS[16];

    const int tid = threadIdx.x;
    const int B0  = blockIdx.x * 16;
    const bool is_byte = ((const unsigned char*)maskp)[1] != 0;

    const int wv   = tid >> 6;
    const int lane = tid & 63;
    const int q    = lane >> 4;
    const int r15  = lane & 15;

    // E (B operand) fragments resident in VGPRs
    int8v ef[4][4];
#pragma unroll
    for (int nt = 0; nt < 4; ++nt) {
        int n = (wv * 4 + nt) * 16 + r15;
#pragma unroll
        for (int kk4 = 0; kk4 < 4; ++kk4) {
            const unsigned char* src = ws + n * 512 + kk4 * 128 + q * 32;
            int4v lo = *(const int4v*)(src);
            int4v hi = *(const int4v*)(src + 16);
            int8v v;
            v[0] = lo.x; v[1] = lo.y; v[2] = lo.z; v[3] = lo.w;
            v[4] = hi.x; v[5] = hi.y; v[6] = hi.z; v[7] = hi.w;
            ef[nt][kk4] = v;
        }
    }

    const int c5 = tid >> 5;
    const int s5 = tid & 31;

    // ---- init pass 1: m0 = max(emit[0]+tfs) per chain ----
    {
        float lmax = -3.0e38f;
#pragma unroll
        for (int i = 0; i < 4; ++i) {
            int j4 = s5 + 32 * i;
            float4v em = *(const float4v*)(emit + (size_t)(B0 + c5) * CC + 4 * j4);
            float4v tf = *(const float4v*)(tfs + 4 * j4);
            float4v a = em + tf;
            lmax = fmaxf(lmax, fmaxf(fmaxf(a.x, a.y), fmaxf(a.z, a.w)));
        }
        red[c5][s5] = lmax;
    }
    __syncthreads();
    if (tid < 16) {
        float m0 = red[tid][0];
        for (int s = 1; s < 32; ++s) m0 = fmaxf(m0, red[tid][s]);
        Sv[tid]  = m0;
        m0S[tid] = m0;
        mslot[0][tid] = 1.0f;   // M_0 = 1 (P0 stored max-normalized)
        mslot[1][tid] = 0.0f;   // step 1 atomicMax target
        mslot[2][tid] = 0.0f;
        mslot[3][tid] = 0.0f;
        dotS[tid] = 0.0f;
    }
    __syncthreads();
    // ---- init pass 2: store P0 (max = 1) in permuted layout; chain lengths ----
    {
        float m0 = m0S[c5];
#pragma unroll
        for (int i = 0; i < 4; ++i) {
            int pd = s5 + 32 * i;
            int wvv = pd >> 4, rw = pd & 15;
            float f[4];
#pragma unroll
            for (int nt = 0; nt < 4; ++nt) {
                int k = 64 * wvv + 16 * nt + rw;
                f[nt] = __expf(emit[(size_t)(B0 + c5) * CC + k] + tfs[k] - m0);
            }
            int r = 0;
            r = __builtin_amdgcn_cvt_pk_fp8_f32(f[0], f[1], r, false);
            r = __builtin_amdgcn_cvt_pk_fp8_f32(f[2], f[3], r, true);
            *(int*)(&p8[0][0] + c5 * 528 + pd * 4) = r;
        }
        int part = 0;
        for (int k = 0; k < 16; ++k)
            part += mask_at(maskp, is_byte, s5 * 16 + k, B0 + c5) ? 1 : 0;
        red[c5][s5] = (float)part;
    }
    __syncthreads();
    if (tid < 16) {
        int s = 0;
        for (int i = 0; i < 32; ++i) s += (int)red[tid][i];
        lenS[tid] = s;
    }
    __syncthreads();

    int lenR[4];
    float et2e[4];
    float rQ[4];                      // 1/sigma_{t-1} for chains q*4+rr; sigma_0 = 1
#pragma unroll
    for (int rr = 0; rr < 4; ++rr) { lenR[rr] = lenS[q * 4 + rr]; rQ[rr] = 1.0f; }
#pragma unroll
    for (int nt = 0; nt < 4; ++nt)
        et2e[nt] = __expf(t2e[(wv * 4 + nt) * 16 + r15]);

    // exp(emit) pipeline: ex holds step t's exp'd emissions
    const float* eb = emit + (size_t)(BB + B0 + q * 4) * CC + (wv * 64 + r15);
    float ex[16];
#pragma unroll
    for (int nt = 0; nt < 4; ++nt)
#pragma unroll
        for (int rr = 0; rr < 4; ++rr)
            ex[nt * 4 + rr] = __expf(eb[rr * CC + nt * 16]);

    // ---- main loop: ONE __syncthreads per step ----
#pragma unroll 2
    for (int t = 1; t < LL; ++t) {
        const int wp = t & 1;
        const int rp = wp ^ 1;

        // prefetch next step's emit
        const float* ebn = (t < LL - 1) ? (eb + BB * CC) : eb;
        float emn[16];
#pragma unroll
        for (int nt = 0; nt < 4; ++nt)
#pragma unroll
            for (int rr = 0; rr < 4; ++rr)
                emn[nt * 4 + rr] = ebn[rr * CC + nt * 16];

        // sigma_t = 64 * M_{t-1} * (1/sigma_{t-1})   [ratio form — stationary]
        float sig[4], rcv[4];
#pragma unroll
        for (int rr = 0; rr < 4; ++rr) {
            float M1 = mslot[(t - 1) & 3][q * 4 + rr];
            sig[rr] = 64.0f * M1 * rQ[rr];
            rcv[rr] = 1.0f / sig[rr];
            rQ[rr]  = rcv[rr];
        }

        if (wv == 0 && r15 == 0) {
#pragma unroll
            for (int rr = 0; rr < 4; ++rr) mslot[(t + 1) & 3][q * 4 + rr] = 0.0f;
        }

        // A fragments: 8x ds_read_b128
        int8v af[4];
        const unsigned char* pr = &p8[rp][0] + r15 * 528 + q * 32;
#pragma unroll
        for (int kk4 = 0; kk4 < 4; ++kk4) {
            int4v lo = *(const int4v*)(pr + kk4 * 128);
            int4v hi = *(const int4v*)(pr + kk4 * 128 + 16);
            int8v v;
            v[0] = lo.x; v[1] = lo.y; v[2] = lo.z; v[3] = lo.w;
            v[4] = hi.x; v[5] = hi.y; v[6] = hi.z; v[7] = hi.w;
            af[kk4] = v;
        }

        float4v acc[4];
        const float4v z = {0.f, 0.f, 0.f, 0.f};
#pragma unroll
        for (int nt = 0; nt < 4; ++nt) acc[nt] = z;
#pragma unroll
        for (int kk4 = 0; kk4 < 4; ++kk4)
#pragma unroll
            for (int nt = 0; nt < 4; ++nt)
                acc[nt] = __builtin_amdgcn_mfma_scale_f32_16x16x128_f8f6f4(
                    af[kk4], ef[nt][kk4], acc[nt],
                    0, 0,
                    0, 0x7F7F7F7F,
                    0, 0x7F7F7F7F);

        // next step's exp, overlaps MFMA
        float exn[16];
#pragma unroll
        for (int i = 0; i < 16; ++i) exn[i] = __expf(emn[i]);

        // vn = acc * ex; rowmax -> atomicMax into slot t&3
        float rowmax[4] = {0.f, 0.f, 0.f, 0.f};
#pragma unroll
        for (int nt = 0; nt < 4; ++nt)
#pragma unroll
            for (int rr = 0; rr < 4; ++rr) {
                float vn = acc[nt][rr] * ex[nt * 4 + rr];
                acc[nt][rr] = vn;
                rowmax[rr] = fmaxf(rowmax[rr], vn);
            }
#pragma unroll
        for (int rr = 0; rr < 4; ++rr) {
            float mr = rowmax[rr];
            mr = fmaxf(mr, __shfl_xor(mr, 1));
            mr = fmaxf(mr, __shfl_xor(mr, 2));
            mr = fmaxf(mr, __shfl_xor(mr, 4));
            mr = fmaxf(mr, __shfl_xor(mr, 8));
            if (r15 == 0 && t < lenR[rr])
                atomicMax((int*)&mslot[t & 3][q * 4 + rr], __float_as_int(mr)); // vn > 0
        }

        // store A_t = clamp(vn / sigma_t, <=448): max = 2^{g_t-6} ~ 2^{3.8±0.5}
        {
            unsigned char* wrow = &p8[wp][0] + (wv * 16 + r15) * 4;
#pragma unroll
            for (int rr = 0; rr < 4; ++rr) {
                if (t < lenR[rr]) {
                    float p0 = fminf(acc[0][rr] * rcv[rr], 448.0f);
                    float p1 = fminf(acc[1][rr] * rcv[rr], 448.0f);
                    float p2 = fminf(acc[2][rr] * rcv[rr], 448.0f);
                    float p3 = fminf(acc[3][rr] * rcv[rr], 448.0f);
                    int r = 0;
                    r = __builtin_amdgcn_cvt_pk_fp8_f32(p0, p1, r, false);
                    r = __builtin_amdgcn_cvt_pk_fp8_f32(p2, p3, r, true);
                    *(int*)(wrow + (q * 4 + rr) * 528) = r;
                }
            }
        }

        // Sv += log(sigma_t) for active chains; frozen: propagate M forward
        if (wv == 0 && r15 == 0) {
#pragma unroll
            for (int rr = 0; rr < 4; ++rr) {
                int c = q * 4 + rr;
                if (t < lenR[rr]) Sv[c] += __logf(sig[rr]);
                else              mslot[t & 3][c] = mslot[(t - 1) & 3][c];
            }
        }
        // final dot at chain's last active step: A-values (vn/sigma_t);
        // Sv contains log(sigma_t) for this step -> consistent.
#pragma unroll
        for (int rr = 0; rr < 4; ++rr) {
            if (t == lenR[rr] - 1) {
                float part = 0.0f;
#pragma unroll
                for (int nt = 0; nt < 4; ++nt)
                    part += acc[nt][rr] * rcv[rr] * et2e[nt];
                part += __shfl_xor(part, 1);
                part += __shfl_xor(part, 2);
                part += __shfl_xor(part, 4);
                part += __shfl_xor(part, 8);
                if (r15 == 0) atomicAdd(&dotS[q * 4 + rr], part);
            }
        }
#pragma unroll
        for (int i = 0; i < 16; ++i) ex[i] = exn[i];
        eb += BB * CC;
        __syncthreads();
    }

    if (tid < 16)
        ((float*)(ws + WS_LOGZ))[B0 + tid] = Sv[tid] + __logf(dotS[tid]);
}

// ---------------- score ----------------------------------------------------------------
__global__ void score_kernel(const float* __restrict__ emit,
                             const int* __restrict__ target,
                             const void* __restrict__ maskp,
                             const float* __restrict__ trans,
                             const float* __restrict__ tfs,
                             const float* __restrict__ t2e,
                             unsigned char* __restrict__ ws) {
    const bool is_byte = ((const unsigned char*)maskp)[1] != 0;
    int g = blockIdx.x * blockDim.x + threadIdx.x;
    float val = 0.0f;
    for (int e = g; e < LL * BB; e += gridDim.x * blockDim.x) {
        int t = e >> 6, b = e & 63;
        if (mask_at(maskp, is_byte, t, b)) {
            int tg  = target[t * BB + b];
            float v = emit[(size_t)(t * BB + b) * CC + tg];
            if (t > 0) v += trans[(size_t)target[(t - 1) * BB + b] * CC + tg];
            val += v;
        }
    }
    if (blockIdx.x == 0 && threadIdx.x < BB) {
        int b = threadIdx.x;
        val += tfs[target[b]];
        int lo = 0, hi = LL;
        while (lo < hi) {
            int mid = (lo + hi) >> 1;
            if (mask_at(maskp, is_byte, mid, b)) lo = mid + 1; else hi = mid;
        }
        val += t2e[target[(lo - 1) * BB + b]];
    }
    for (int off = 32; off > 0; off >>= 1) val += __shfl_down(val, off);
    if ((threadIdx.x & 63) == 0) atomicAdd((float*)(ws + WS_SCORE), val);
}

__global__ void combine_kernel(const unsigned char* __restrict__ ws, float* __restrict__ out) {
    float v = ((const float*)(ws + WS_LOGZ))[threadIdx.x];
    for (int off = 32; off > 0; off >>= 1) v += __shfl_down(v, off);
    if (threadIdx.x == 0) out[0] = (v - *(const float*)(ws + WS_SCORE)) * (1.0f / 64.0f);
}

extern "C" void kernel_launch(void* const* d_in, const int* in_sizes, int n_in,
                              void* d_out, int out_size, void* d_ws, size_t ws_size,
                              hipStream_t stream) {
    const float* emit   = (const float*)d_in[0];
    const int*   target = (const int*)d_in[1];
    const void*  maskp  = d_in[2];
    const float* trans  = (const float*)d_in[3];
    const float* tfs    = (const float*)d_in[4];
    const float* t2e    = (const float*)d_in[5];
    unsigned char* ws   = (unsigned char*)d_ws;
    float* out          = (float*)d_out;

    prep_kernel<<<256, 256, 0, stream>>>(trans, ws);
    crf_scan_kernel<<<4, 512, 0, stream>>>(emit, maskp, tfs, t2e, ws);
    score_kernel<<<32, 256, 0, stream>>>(emit, target, maskp, trans, tfs, t2e, ws);
    combine_kernel<<<1, 64, 0, stream>>>(ws, out);
}

// Round 8
// 968.042 us; speedup vs baseline: 1.6399x; 1.1910x over previous
//
#include <hip/hip_runtime.h>
#include <hip/hip_bf16.h>
#include <stdint.h>

#define LL 512
#define BB 64
#define CC 512

typedef float float4v __attribute__((ext_vector_type(4)));
typedef int   int4v   __attribute__((ext_vector_type(4)));
typedef int   int8v   __attribute__((ext_vector_type(8)));

#define WS_SCORE 262144
#define WS_LOGZ  262148

// position permutation shared by p8 rows and E8T columns:
//   k_perm(P) = 64*(P>>6) + 16*(P&3) + ((P>>2)&15)

__device__ __forceinline__ bool mask_at(const void* maskp, bool is_byte, int t, int b) {
    if (is_byte) return ((const unsigned char*)maskp)[t * BB + b] != 0;
    return ((const int*)maskp)[t * BB + b] != 0;
}

// 16-lane (DPP row) max reduce: after this, all 16 lanes of the row hold the max.
__device__ __forceinline__ float rowmax16_dpp(float x) {
    int t;
    t = __builtin_amdgcn_update_dpp(0, __float_as_int(x), 0x128, 0xF, 0xF, true); // ror:8
    x = fmaxf(x, __int_as_float(t));
    t = __builtin_amdgcn_update_dpp(0, __float_as_int(x), 0x124, 0xF, 0xF, true); // ror:4
    x = fmaxf(x, __int_as_float(t));
    t = __builtin_amdgcn_update_dpp(0, __float_as_int(x), 0x122, 0xF, 0xF, true); // ror:2
    x = fmaxf(x, __int_as_float(t));
    t = __builtin_amdgcn_update_dpp(0, __float_as_int(x), 0x121, 0xF, 0xF, true); // ror:1
    x = fmaxf(x, __int_as_float(t));
    return x;
}

__global__ void prep_kernel(const float* __restrict__ trans, unsigned char* __restrict__ ws) {
    int g = blockIdx.x * blockDim.x + threadIdx.x;
    if (g == 0) *(float*)(ws + WS_SCORE) = 0.0f;
    if (g >= 512 * 128) return;
    int n  = g & 511;
    int pd = g >> 9;
    int wv = pd >> 4, rw = pd & 15;
    float f[4];
#pragma unroll
    for (int nt = 0; nt < 4; ++nt) {
        int k = 64 * wv + 16 * nt + rw;
        f[nt] = __expf(trans[(size_t)k * CC + n]);
    }
    int r = 0;
    r = __builtin_amdgcn_cvt_pk_fp8_f32(f[0], f[1], r, false);
    r = __builtin_amdgcn_cvt_pk_fp8_f32(f[2], f[3], r, true);
    ((int*)ws)[n * 128 + pd] = r;
}

// ---------------- main scan: ONE barrier per step, self-normalizing stale scale --------
// sigma_t = 64 * M_{t-1} / sigma_{t-1} (ratio form; stored-max_t = 2^{g_t-6}, memoryless).
// Dead chains (t >= len) run UNGUARDED: their P rows / mslot entries are garbage but
// only feed their own (dead) C rows; Sv and the final dot are taken before death.
__launch_bounds__(512, 2)
__global__ void crf_scan_kernel(const float* __restrict__ emit,
                                const void* __restrict__ maskp,
                                const float* __restrict__ tfs,
                                const float* __restrict__ t2e,
                                unsigned char* __restrict__ ws) {
    __shared__ __align__(16) unsigned char p8[2][16 * 528];
    __shared__ float mslot[4][16];   // rowmax ring; slot t&3 written at step t
    __shared__ float Sv[16];
    __shared__ float dotS[16];
    __shared__ float m0S[16];
    __shared__ float red[16][32];
    __shared__ int   lenS[16];

    const int tid = threadIdx.x;
    const int B0  = blockIdx.x * 16;
    const bool is_byte = ((const unsigned char*)maskp)[1] != 0;

    const int wv   = tid >> 6;
    const int lane = tid & 63;
    const int q    = lane >> 4;
    const int r15  = lane & 15;

    // E (B operand) fragments resident in VGPRs
    int8v ef[4][4];
#pragma unroll
    for (int nt = 0; nt < 4; ++nt) {
        int n = (wv * 4 + nt) * 16 + r15;
#pragma unroll
        for (int kk4 = 0; kk4 < 4; ++kk4) {
            const unsigned char* src = ws + n * 512 + kk4 * 128 + q * 32;
            int4v lo = *(const int4v*)(src);
            int4v hi = *(const int4v*)(src + 16);
            ef[nt][kk4] = __builtin_shufflevector(lo, hi, 0, 1, 2, 3, 4, 5, 6, 7);
        }
    }

    const int c5 = tid >> 5;
    const int s5 = tid & 31;

    // ---- init pass 1: m0 = max(emit[0]+tfs) per chain ----
    {
        float lmax = -3.0e38f;
#pragma unroll
        for (int i = 0; i < 4; ++i) {
            int j4 = s5 + 32 * i;
            float4v em = *(const float4v*)(emit + (size_t)(B0 + c5) * CC + 4 * j4);
            float4v tf = *(const float4v*)(tfs + 4 * j4);
            float4v a = em + tf;
            lmax = fmaxf(lmax, fmaxf(fmaxf(a.x, a.y), fmaxf(a.z, a.w)));
        }
        red[c5][s5] = lmax;
    }
    __syncthreads();
    if (tid < 16) {
        float m0 = red[tid][0];
        for (int s = 1; s < 32; ++s) m0 = fmaxf(m0, red[tid][s]);
        Sv[tid]  = m0;
        m0S[tid] = m0;
        mslot[0][tid] = 1.0f;   // M_0 = 1 (P0 stored max-normalized)
        mslot[1][tid] = 0.0f;   // step 1 atomicMax target
        mslot[2][tid] = 0.0f;
        mslot[3][tid] = 0.0f;
        dotS[tid] = 0.0f;
    }
    __syncthreads();
    // ---- init pass 2: store P0 (max = 1) in permuted layout; chain lengths ----
    {
        float m0 = m0S[c5];
#pragma unroll
        for (int i = 0; i < 4; ++i) {
            int pd = s5 + 32 * i;
            int wvv = pd >> 4, rw = pd & 15;
            float f[4];
#pragma unroll
            for (int nt = 0; nt < 4; ++nt) {
                int k = 64 * wvv + 16 * nt + rw;
                f[nt] = __expf(emit[(size_t)(B0 + c5) * CC + k] + tfs[k] - m0);
            }
            int r = 0;
            r = __builtin_amdgcn_cvt_pk_fp8_f32(f[0], f[1], r, false);
            r = __builtin_amdgcn_cvt_pk_fp8_f32(f[2], f[3], r, true);
            *(int*)(&p8[0][0] + c5 * 528 + pd * 4) = r;
        }
        int part = 0;
        for (int k = 0; k < 16; ++k)
            part += mask_at(maskp, is_byte, s5 * 16 + k, B0 + c5) ? 1 : 0;
        red[c5][s5] = (float)part;
    }
    __syncthreads();
    if (tid < 16) {
        int s = 0;
        for (int i = 0; i < 32; ++i) s += (int)red[tid][i];
        lenS[tid] = s;
    }
    __syncthreads();

    int lenR[4];
    float et2e[4];
    float rQ[4];                      // 1/sigma_{t-1}; sigma_0 = 1
#pragma unroll
    for (int rr = 0; rr < 4; ++rr) { lenR[rr] = lenS[q * 4 + rr]; rQ[rr] = 1.0f; }
#pragma unroll
    for (int nt = 0; nt < 4; ++nt)
        et2e[nt] = __expf(t2e[(wv * 4 + nt) * 16 + r15]);

    // exp(emit) pipeline; two bases keep all offsets within 13-bit immediates
    const float* eb0 = emit + (size_t)(BB + B0 + q * 4) * CC + (wv * 64 + r15);
    const float* eb1 = eb0 + 2 * CC;
    float ex[16];
#pragma unroll
    for (int nt = 0; nt < 4; ++nt) {
#pragma unroll
        for (int rr = 0; rr < 2; ++rr) {
            ex[nt * 4 + rr]     = __expf(eb0[rr * CC + nt * 16]);
            ex[nt * 4 + rr + 2] = __expf(eb1[rr * CC + nt * 16]);
        }
    }

    // ---- main loop: ONE __syncthreads per step ----
#pragma unroll 2
    for (int t = 1; t < LL; ++t) {
        const int wp = t & 1;
        const int rp = wp ^ 1;

        // prefetch next step's emit
        const size_t step = (t < LL - 1) ? (size_t)(BB * CC) : 0;
        float emn[16];
#pragma unroll
        for (int nt = 0; nt < 4; ++nt) {
#pragma unroll
            for (int rr = 0; rr < 2; ++rr) {
                emn[nt * 4 + rr]     = eb0[step + rr * CC + nt * 16];
                emn[nt * 4 + rr + 2] = eb1[step + rr * CC + nt * 16];
            }
        }

        // A fragments: 8x ds_read_b128 (issue ASAP after barrier)
        int8v af[4];
        const unsigned char* pr = &p8[rp][0] + r15 * 528 + q * 32;
#pragma unroll
        for (int kk4 = 0; kk4 < 4; ++kk4) {
            int4v lo = *(const int4v*)(pr + kk4 * 128);
            int4v hi = *(const int4v*)(pr + kk4 * 128 + 16);
            af[kk4] = __builtin_shufflevector(lo, hi, 0, 1, 2, 3, 4, 5, 6, 7);
        }

        // sigma_t = 64 * M_{t-1} * (1/sigma_{t-1})   [ratio form]
        float sig[4], rcv[4];
#pragma unroll
        for (int rr = 0; rr < 4; ++rr) {
            float M1 = mslot[(t - 1) & 3][q * 4 + rr];
            sig[rr] = 64.0f * M1 * rQ[rr];
            rcv[rr] = 1.0f / sig[rr];
            rQ[rr]  = rcv[rr];
        }

        if (wv == 0 && r15 == 0) {
#pragma unroll
            for (int rr = 0; rr < 4; ++rr) mslot[(t + 1) & 3][q * 4 + rr] = 0.0f;
        }

        float4v acc[4];
        const float4v z = {0.f, 0.f, 0.f, 0.f};
#pragma unroll
        for (int nt = 0; nt < 4; ++nt) acc[nt] = z;

        // MFMA pair 1: nt = 0,1 (two dependent chains in flight)
#pragma unroll
        for (int kk4 = 0; kk4 < 4; ++kk4)
#pragma unroll
            for (int nt = 0; nt < 2; ++nt)
                acc[nt] = __builtin_amdgcn_mfma_scale_f32_16x16x128_f8f6f4(
                    af[kk4], ef[nt][kk4], acc[nt],
                    0, 0, 0, 0x7F7F7F7F, 0, 0x7F7F7F7F);

        // next step's exp (VALU) — overlaps MFMA issue
        float exn[16];
#pragma unroll
        for (int i = 0; i < 16; ++i) exn[i] = __expf(emn[i]);

        // MFMA pair 2: nt = 2,3
#pragma unroll
        for (int kk4 = 0; kk4 < 4; ++kk4)
#pragma unroll
            for (int nt = 2; nt < 4; ++nt)
                acc[nt] = __builtin_amdgcn_mfma_scale_f32_16x16x128_f8f6f4(
                    af[kk4], ef[nt][kk4], acc[nt],
                    0, 0, 0, 0x7F7F7F7F, 0, 0x7F7F7F7F);

        // epilogue pair 1 (overlaps MFMA pair 2): vn, partial rowmax
        float rowmax[4];
#pragma unroll
        for (int rr = 0; rr < 4; ++rr) {
            float v0 = acc[0][rr] * ex[0 * 4 + rr];
            float v1 = acc[1][rr] * ex[1 * 4 + rr];
            acc[0][rr] = v0; acc[1][rr] = v1;
            rowmax[rr] = fmaxf(v0, v1);
        }
        // epilogue pair 2
#pragma unroll
        for (int rr = 0; rr < 4; ++rr) {
            float v2 = acc[2][rr] * ex[2 * 4 + rr];
            float v3 = acc[3][rr] * ex[3 * 4 + rr];
            acc[2][rr] = v2; acc[3][rr] = v3;
            rowmax[rr] = fmaxf(rowmax[rr], fmaxf(v2, v3));
        }

        // store A_t = clamp(vn/sigma_t, <=448) — UNGUARDED (dead rows are write-only)
        {
            unsigned char* wrow = &p8[wp][0] + (wv * 16 + r15) * 4;
#pragma unroll
            for (int rr = 0; rr < 4; ++rr) {
                float p0 = fminf(acc[0][rr] * rcv[rr], 448.0f);
                float p1 = fminf(acc[1][rr] * rcv[rr], 448.0f);
                float p2 = fminf(acc[2][rr] * rcv[rr], 448.0f);
                float p3 = fminf(acc[3][rr] * rcv[rr], 448.0f);
                int r = 0;
                r = __builtin_amdgcn_cvt_pk_fp8_f32(p0, p1, r, false);
                r = __builtin_amdgcn_cvt_pk_fp8_f32(p2, p3, r, true);
                *(int*)(wrow + (q * 4 + rr) * 528) = r;
            }
        }

        // cross-lane max via DPP (VALU, ~8 instr); lane 0 of each row does the atomic
#pragma unroll
        for (int rr = 0; rr < 4; ++rr) {
            float mr = rowmax16_dpp(rowmax[rr]);
            if (r15 == 0)
                atomicMax((int*)&mslot[t & 3][q * 4 + rr], __float_as_int(mr)); // UNGUARDED
        }

        // Sv += log(sigma_t) — guarded (must freeze at chain end)
        if (wv == 0 && r15 == 0) {
#pragma unroll
            for (int rr = 0; rr < 4; ++rr)
                if (t < lenR[rr]) Sv[q * 4 + rr] += __logf(sig[rr]);
        }
        // final dot at chain's last active step (guarded; uniform across the 16-lane row)
#pragma unroll
        for (int rr = 0; rr < 4; ++rr) {
            if (t == lenR[rr] - 1) {
                float part = 0.0f;
#pragma unroll
                for (int nt = 0; nt < 4; ++nt)
                    part += acc[nt][rr] * rcv[rr] * et2e[nt];
                part += __shfl_xor(part, 1);
                part += __shfl_xor(part, 2);
                part += __shfl_xor(part, 4);
                part += __shfl_xor(part, 8);
                if (r15 == 0) atomicAdd(&dotS[q * 4 + rr], part);
            }
        }
#pragma unroll
        for (int i = 0; i < 16; ++i) ex[i] = exn[i];
        eb0 += BB * CC;
        eb1 += BB * CC;
        __syncthreads();
    }

    if (tid < 16)
        ((float*)(ws + WS_LOGZ))[B0 + tid] = Sv[tid] + __logf(dotS[tid]);
}

// ---------------- score ----------------------------------------------------------------
__global__ void score_kernel(const float* __restrict__ emit,
                             const int* __restrict__ target,
                             const void* __restrict__ maskp,
                             const float* __restrict__ trans,
                             const float* __restrict__ tfs,
                             const float* __restrict__ t2e,
                             unsigned char* __restrict__ ws) {
    const bool is_byte = ((const unsigned char*)maskp)[1] != 0;
    int g = blockIdx.x * blockDim.x + threadIdx.x;
    float val = 0.0f;
    for (int e = g; e < LL * BB; e += gridDim.x * blockDim.x) {
        int t = e >> 6, b = e & 63;
        if (mask_at(maskp, is_byte, t, b)) {
            int tg  = target[t * BB + b];
            float v = emit[(size_t)(t * BB + b) * CC + tg];
            if (t > 0) v += trans[(size_t)target[(t - 1) * BB + b] * CC + tg];
            val += v;
        }
    }
    if (blockIdx.x == 0 && threadIdx.x < BB) {
        int b = threadIdx.x;
        val += tfs[target[b]];
        int lo = 0, hi = LL;
        while (lo < hi) {
            int mid = (lo + hi) >> 1;
            if (mask_at(maskp, is_byte, mid, b)) lo = mid + 1; else hi = mid;
        }
        val += t2e[target[(lo - 1) * BB + b]];
    }
    for (int off = 32; off > 0; off >>= 1) val += __shfl_down(val, off);
    if ((threadIdx.x & 63) == 0) atomicAdd((float*)(ws + WS_SCORE), val);
}

__global__ void combine_kernel(const unsigned char* __restrict__ ws, float* __restrict__ out) {
    float v = ((const float*)(ws + WS_LOGZ))[threadIdx.x];
    for (int off = 32; off > 0; off >>= 1) v += __shfl_down(v, off);
    if (threadIdx.x == 0) out[0] = (v - *(const float*)(ws + WS_SCORE)) * (1.0f / 64.0f);
}

extern "C" void kernel_launch(void* const* d_in, const int* in_sizes, int n_in,
                              void* d_out, int out_size, void* d_ws, size_t ws_size,
                              hipStream_t stream) {
    const float* emit   = (const float*)d_in[0];
    const int*   target = (const int*)d_in[1];
    const void*  maskp  = d_in[2];
    const float* trans  = (const float*)d_in[3];
    const float* tfs    = (const float*)d_in[4];
    const float* t2e    = (const float*)d_in[5];
    unsigned char* ws   = (unsigned char*)d_ws;
    float* out          = (float*)d_out;

    prep_kernel<<<256, 256, 0, stream>>>(trans, ws);
    crf_scan_kernel<<<4, 512, 0, stream>>>(emit, maskp, tfs, t2e, ws);
    score_kernel<<<32, 256, 0, stream>>>(emit, target, maskp, trans, tfs, t2e, ws);
    combine_kernel<<<1, 64, 0, stream>>>(ws, out);
}